// Round 11
// baseline (116.056 us; speedup 1.0000x reference)
//
#include <hip/hip_runtime.h>

// B=2, D=64, N=512, H=256, OUT=64
// mid[b] = sum_{c,i} relu( relu(hi[b,i,:]+hcb[b,c,:]) @ w2 + b2 ) @ w3 + N^2*b3
// out = relu(mid @ w4 + b4) @ w5 + b5
//
// big v10b: 512 blocks x 4 waves. Block tile = 32 pair-rows (4c x 8i) x 256 cols,
// 32 tiles (i-octets) per block. acc = 2xf32x16 (32 regs), bfr 128 regs.
// Gen interleaved per-chunk into the MFMA loop: chunk j gens rows {j, j+8}
// (one hv load each, 2-deep pipelined, <=3 live), writes next tile's LDS buf.
// One barrier per tile. Partials: [batch][col][blk] (v10's indexing bug fixed).

using f32x16  = __attribute__((ext_vector_type(16))) float;
using short8  = __attribute__((ext_vector_type(8))) short;
using float2v = __attribute__((ext_vector_type(2))) float;
using float4v = __attribute__((ext_vector_type(4))) float;

__device__ __forceinline__ short f2bf(float f) {
    unsigned u = __float_as_uint(f);
    unsigned r = u + 0x7FFFu + ((u >> 16) & 1u);   // RNE
    return (short)(r >> 16);
}

// ---- prep (merged): blocks [0,1024): hi/hcb; blocks [1024,1280): w2t transpose
__global__ __launch_bounds__(256) void prep(const float* __restrict__ in,
                                            const float* __restrict__ w1,
                                            const float* __restrict__ b1,
                                            const float* __restrict__ w2,
                                            float* __restrict__ hi,
                                            float* __restrict__ hcb,
                                            short* __restrict__ w2t) {
    int tid = threadIdx.x;
    int bidx = blockIdx.x;
    if (bidx < 1024) {
        int b = bidx >> 9, n = bidx & 511;
        __shared__ float xs[64];
        if (tid < 64) xs[tid] = in[(size_t)(b * 64 + tid) * 512 + n];
        __syncthreads();
        float a0 = 0.f, a1 = 0.f;
#pragma unroll 8
        for (int d = 0; d < 64; ++d) {
            float xv = xs[d];
            a0 += xv * w1[d * 256 + tid];
            a1 += xv * w1[(64 + d) * 256 + tid];
        }
        size_t o = (size_t)(b * 512 + n) * 256 + tid;
        hi[o]  = a0;
        hcb[o] = a1 + b1[tid];
    } else {
        int idx = (bidx - 1024) * 256 + tid;
        int n = idx & 255, k = idx >> 8;
        w2t[n * 256 + k] = f2bf(w2[k * 256 + n]);
    }
}

// ---- big v10b
__global__ __launch_bounds__(256, 2) void big(const float* __restrict__ hi,
                                              const float* __restrict__ hcb,
                                              const short* __restrict__ w2t,
                                              const float* __restrict__ b2,
                                              float* __restrict__ partials) {
    __shared__ __align__(16) unsigned tA[2][32 * 128];   // 2 x 16 KB

    const int tid = threadIdx.x;
    const int bid = blockIdx.x;                 // [0,512)
    const int b = bid >> 8, cq = (bid >> 1) & 127, ihf = bid & 1;

    const float* __restrict__ hib  = hi  + (size_t)b * 131072;
    const float* __restrict__ hcbb = hcb + (size_t)b * 131072;

    const int cp   = tid & 127, half = tid >> 7;   // gen mapping
    const int lane = tid & 63,  wid  = tid >> 6;   // MFMA mapping
    const int h = lane >> 5, l31 = lane & 31, l7 = lane & 7;
    const int colbase = wid * 64;

    // context rows: c-rows cq*4 + 2*half + {0,1}
    float2v cv2[2];
#pragma unroll
    for (int m = 0; m < 2; ++m)
        cv2[m] = *reinterpret_cast<const float2v*>(
            &hcbb[(size_t)(cq * 4 + 2 * half + m) * 256 + 2 * cp]);

    // persistent B fragments: 64 cols x K=256 per wave (128 regs)
    short8 bfr[2][16];
    const short8* w2v = reinterpret_cast<const short8*>(w2t);
#pragma unroll
    for (int cb = 0; cb < 2; ++cb)
#pragma unroll
        for (int kk = 0; kk < 16; ++kk)
            bfr[cb][kk] = w2v[(size_t)(colbase + cb * 32 + l31) * 32 + kk * 2 + h];

    const float b2v0 = b2[colbase + l31];
    const float b2v1 = b2[colbase + 32 + l31];
    float psum0 = 0.f, psum1 = 0.f;

    const int cbase = cp >> 2, woff = cp & 3;

    // ---- prologue: gen tile 0 (io = ihf*32)
    {
        const float* hs = &hib[(size_t)(ihf * 32 * 8) * 256 + 2 * cp];
        float2v hv[8];
#pragma unroll
        for (int j = 0; j < 8; ++j)
            hv[j] = *reinterpret_cast<const float2v*>(hs + (size_t)j * 256);
#pragma unroll
        for (int rr = 0; rr < 16; ++rr) {
            const int m = rr >> 3, ii = rr & 7;
            const int r = half * 16 + rr;
            float ax = hv[ii][0] + cv2[m][0];
            float ay = hv[ii][1] + cv2[m][1];
            ax = fmaxf(ax, 0.f);
            ay = fmaxf(ay, 0.f);
            unsigned pk;
            asm("v_cvt_pk_bf16_f32 %0, %1, %2" : "=v"(pk) : "v"(ax), "v"(ay));
            tA[0][r * 128 + (((cbase ^ ii) << 2) + woff)] = pk;
        }
    }
    __syncthreads();

#pragma unroll 1
    for (int t = 0; t < 32; ++t) {
        const int cur = t & 1;
        const short8* __restrict__ tAv = reinterpret_cast<const short8*>(tA[cur]);
        unsigned* __restrict__ wbuf = tA[cur ^ 1];
        const bool hn = (t < 31);
        const float* hsrc = &hib[(size_t)((ihf * 32 + t + 1) * 8) * 256 + 2 * cp];

        f32x16 A0, A1;
#pragma unroll
        for (int e = 0; e < 16; ++e) { A0[e] = b2v0; A1[e] = b2v1; }

        float2v hv[8];
        if (hn) {
            hv[0] = *reinterpret_cast<const float2v*>(hsrc);
            hv[1] = *reinterpret_cast<const float2v*>(hsrc + 256);
        }

#pragma unroll
        for (int j = 0; j < 8; ++j) {
            if (hn && j < 6)
                hv[j + 2] = *reinterpret_cast<const float2v*>(hsrc + (size_t)(j + 2) * 256);

            // MFMA pair: kk = 2j, 2j+1
#pragma unroll
            for (int e2 = 0; e2 < 2; ++e2) {
                const int kk = 2 * j + e2;
                const int sc = (kk * 2 + h) ^ l7;
                short8 a = tAv[l31 * 32 + sc];
                __builtin_amdgcn_s_setprio(1);
                A0 = __builtin_amdgcn_mfma_f32_32x32x16_bf16(a, bfr[0][kk], A0, 0, 0, 0);
                A1 = __builtin_amdgcn_mfma_f32_32x32x16_bf16(a, bfr[1][kk], A1, 0, 0, 0);
                __builtin_amdgcn_s_setprio(0);
            }

            // gen chunk j of tile t+1: rows half*16 + j and half*16 + 8 + j
            if (hn) {
                const int r1 = half * 16 + j;
                const int wofs = ((cbase ^ j) << 2) + woff;
                float ax = hv[j][0] + cv2[0][0];
                float ay = hv[j][1] + cv2[0][1];
                ax = fmaxf(ax, 0.f);
                ay = fmaxf(ay, 0.f);
                unsigned pk0;
                asm("v_cvt_pk_bf16_f32 %0, %1, %2" : "=v"(pk0) : "v"(ax), "v"(ay));
                wbuf[r1 * 128 + wofs] = pk0;
                float bx = hv[j][0] + cv2[1][0];
                float by = hv[j][1] + cv2[1][1];
                bx = fmaxf(bx, 0.f);
                by = fmaxf(by, 0.f);
                unsigned pk1;
                asm("v_cvt_pk_bf16_f32 %0, %1, %2" : "=v"(pk1) : "v"(bx), "v"(by));
                wbuf[(r1 + 8) * 128 + wofs] = pk1;
            }
        }

        float s0 = 0.f, s1 = 0.f;
#pragma unroll
        for (int e = 0; e < 16; ++e) {
            s0 += fmaxf(A0[e], 0.f);
            s1 += fmaxf(A1[e], 0.f);
        }
        psum0 += s0;
        psum1 += s1;
        __syncthreads();
    }

    psum0 += __shfl_xor(psum0, 32);
    psum1 += __shfl_xor(psum1, 32);
    if (h == 0) {
        // partials layout: [batch][col][blk], blk = bid & 255
        const int blk = bid & 255;
        partials[((size_t)(b * 256 + colbase + l31)) * 256 + blk]      = psum0;
        partials[((size_t)(b * 256 + colbase + 32 + l31)) * 256 + blk] = psum1;
    }
}

// ---- final: coalesced reduce ([batch][col][256 blk]) + tail MLP, 512 thr
__global__ __launch_bounds__(512) void finalK(const float* __restrict__ partials,
                                              const float* __restrict__ w3,
                                              const float* __restrict__ b3,
                                              const float* __restrict__ w4,
                                              const float* __restrict__ b4,
                                              const float* __restrict__ w5,
                                              const float* __restrict__ b5,
                                              float* __restrict__ out) {
    __shared__ float su[2][256], mid[2][256], o[2][256];
    int tid = threadIdx.x;
    int b = tid >> 8, c = tid & 255;
    const float4v* pv = reinterpret_cast<const float4v*>(
        partials + ((size_t)(b * 256 + c)) * 256);
    float s = 0.f;
#pragma unroll 8
    for (int r = 0; r < 64; ++r) {
        float4v v = pv[r];
        s += v[0] + v[1] + v[2] + v[3];
    }
    su[b][c] = s;
    __syncthreads();
    float m = 262144.0f * b3[c];
    for (int k = 0; k < 256; ++k) m += su[b][k] * w3[k * 256 + c];
    mid[b][c] = m;
    __syncthreads();
    float ov = b4[c];
    for (int k = 0; k < 256; ++k) ov += mid[b][k] * w4[k * 256 + c];
    o[b][c] = fmaxf(ov, 0.f);
    __syncthreads();
    if (c < 64) {
        float r = b5[c];
        for (int k = 0; k < 256; ++k) r += o[b][k] * w5[k * 64 + c];
        out[b * 64 + c] = r;
    }
}

extern "C" void kernel_launch(void* const* d_in, const int* in_sizes, int n_in,
                              void* d_out, int out_size, void* d_ws, size_t ws_size,
                              hipStream_t stream) {
    const float* in = (const float*)d_in[0];
    const float* w1 = (const float*)d_in[1];
    const float* b1 = (const float*)d_in[2];
    const float* w2 = (const float*)d_in[3];
    const float* b2 = (const float*)d_in[4];
    const float* w3 = (const float*)d_in[5];
    const float* b3 = (const float*)d_in[6];
    const float* w4 = (const float*)d_in[7];
    const float* b4 = (const float*)d_in[8];
    const float* w5 = (const float*)d_in[9];
    const float* b5 = (const float*)d_in[10];
    float* out = (float*)d_out;

    char* ws = (char*)d_ws;
    float* hi       = (float*)(ws);                                   // 1 MB
    float* hcb      = (float*)(ws + (1u << 20));                      // 1 MB
    short* w2t      = (short*)(ws + (2u << 20));                      // 128 KB
    float* partials = (float*)(ws + (2u << 20) + (1u << 18));         // 512 KB (2x256x256)

    prep<<<1280, 256, 0, stream>>>(in, w1, b1, w2, hi, hcb, w2t);
    big<<<512, 256, 0, stream>>>(hi, hcb, w2t, b2, partials);
    finalK<<<1, 512, 0, stream>>>(partials, w3, b3, w4, b4, w5, b5, out);
}